// Round 9
// baseline (649.655 us; speedup 1.0000x reference)
//
#include <hip/hip_runtime.h>
#include <hip/hip_bf16.h>
#include <math.h>

namespace {

constexpr int kN0 = 100000, kN1 = 25000, kN2 = 6250;
constexpr int kE0 = 1600000, kE1 = 400000, kE2 = 100000;
// Concatenated-edge layout: [A0 | A1 | A2 | T0(assign0) | T1(assign1)]
constexpr int kEO1 = kE0;                   // 1,600,000
constexpr int kEO2 = kEO1 + kE1;            // 2,000,000
constexpr int kEO3 = kEO2 + kE2;            // 2,100,000
constexpr int kEO4 = kEO3 + kN0;            // 2,200,000
constexpr int kTE  = kEO4 + kN1;            // 2,225,000
// Concatenated-bin layout (destination node counts per graph)
constexpr int kBO1 = kN0;                   // A1 bins
constexpr int kBO2 = kBO1 + kN1;            // A2 bins
constexpr int kBO3 = kBO2 + kN2;            // T0 bins
constexpr int kBO4 = kBO3 + kN1;            // T1 bins
constexpr int kTB  = kBO4 + kN2;            // 162,500 total bins

// ---- two-level bucket sort geometry ----
// r9: sortblk writes records DIRECTLY (scattered) into its own contiguous
// 32KB stag region. The region is block-private -> no cross-block line
// sharing (r7's 2.6x amp) and stays L2-resident until complete -> one
// writeback per line. r8's LDS recs staging gave no write win and cost
// occupancy (38.9KB LDS -> 37%) + 642K LDS bank conflicts; removed.
constexpr int kFB  = 256;                   // fine bins per bucket
constexpr int kNCB = (kTB + kFB - 1) / kFB; // 635 coarse buckets
constexpr int kEPB = 4096;                  // edges per sortblk block
constexpr int kNBA = (kTE + kEPB - 1) / kEPB;  // 544 blocks
constexpr int kGN  = kNCB * kNBA;           // 345,440 (bucket-major G matrix)
constexpr int kScanElems = 4096;            // elems per scan1 block (16/thread)
constexpr int kNBLK_G = (kGN + kScanElems - 1) / kScanElems;  // 85 (<=256 ok)

// Bucket record cap for LDS staging in finesort: avg bucket = 4096 edges,
// sigma ~ 64 (multinomial) -> 4352 = avg + 4 sigma. Fallback path if bigger.
constexpr int kCap = 4352;                  // 34.8KB of int2 in LDS

constexpr int kGemmRows = 32;               // fused gemm tile rows (256 thr)
constexpr int kGemmBlocks = (kN0 + kGemmRows - 1) / kGemmRows;  // 3,125

// sortblk LDS union layout (bytes): sort path 6,104 / gemm path 16,896.
constexpr int kHOff     = 0;                // int[635]    = 2540
constexpr int kLocOff   = 2540;             // int[635]    = 2540
constexpr int kSdataOff = 5080;             // int[256]    = 1024
constexpr int kSmemSz   = 16896;            // max(6104, 32*132*4)

__device__ __forceinline__ float bf_lo(unsigned int u) {
  return __uint_as_float(u << 16);
}
__device__ __forceinline__ float bf_hi(unsigned int u) {
  return __uint_as_float(u & 0xffff0000u);
}
__device__ __forceinline__ unsigned short f2bf(float f) {
  __hip_bfloat16 h = __float2bfloat16(f);
  return *reinterpret_cast<unsigned short*>(&h);
}

// edge id -> (dst, boff) for count; full decode for place
__device__ __forceinline__ void edge_bin(
    int t, const int* a0i, const int* a1i, const int* a2i,
    const int* as0, const int* as1, int& dst, int& boff) {
  if (t < kEO1)      { dst = a0i[t];        boff = 0;    }
  else if (t < kEO2) { dst = a1i[t - kEO1]; boff = kBO1; }
  else if (t < kEO3) { dst = a2i[t - kEO2]; boff = kBO2; }
  else if (t < kEO4) { dst = as0[t - kEO3]; boff = kBO3; }
  else               { dst = as1[t - kEO4]; boff = kBO4; }
}

__device__ __forceinline__ void edge_decode(
    int t, const int* a0i, const float* a0v, const int* a1i, const int* a2i,
    const int* as0, const int* as1, int& dst, int& src, int& boff, float& val) {
  if (t < kEO1)      { dst = a0i[t]; src = a0i[kE0 + t]; val = a0v[t]; boff = 0; }
  else if (t < kEO2) { int e = t - kEO1; dst = a1i[e]; src = a1i[kE1 + e]; val = 1.0f; boff = kBO1; }
  else if (t < kEO3) { int e = t - kEO2; dst = a2i[e]; src = a2i[kE2 + e]; val = 1.0f; boff = kBO2; }
  else if (t < kEO4) { int e = t - kEO3; dst = as0[e]; src = e;            val = 1.0f; boff = kBO3; }
  else               { int e = t - kEO4; dst = as1[e]; src = e;            val = 1.0f; boff = kBO4; }
}

// ---------------------------------------------------------------------------
// CSR build via two-level bucket sort — ZERO global atomics:
//  sortblk: per-block count (LDS hist over 635 buckets) -> LDS scan ->
//           direct scattered store of records (fine idx in rec.x[31:24],
//           src < 2^24) into the block's PRIVATE 32KB stag region.
//           Emits G counts + Loc local offsets. gc1 GEMM blocks ride along.
//  scan:    exclusive scan of G (bucket-major): Gs[b][k]-Gs[b][0] = fragment
//           offset of block k within bucket b; Gs[b][0] = bucket start.
//  finesort: one block per bucket; gathers its 544 fragments via LDS binary
//           search over the (contiguous) G/Loc rows, stages in LDS, then
//           fine-sorts 256 bins -> row_ptr + final edges.
// ---------------------------------------------------------------------------

__global__ __launch_bounds__(256) void sortblk_gemm_kernel(
    const int* __restrict__ a0i, const float* __restrict__ a0v,
    const int* __restrict__ a1i, const int* __restrict__ a2i,
    const int* __restrict__ as0, const int* __restrict__ as1,
    int* __restrict__ G, int* __restrict__ Loc, int2* __restrict__ stag,
    const float* __restrict__ A, const float* __restrict__ W,
    unsigned short* __restrict__ Cb, int M) {
  __shared__ __align__(16) unsigned char smem[kSmemSz];
  int t = threadIdx.x;
  if (blockIdx.x < kNBA) {
    int* h   = (int*)(smem + kHOff);     // counts, then bump cursors
    int* loc = (int*)(smem + kLocOff);   // exclusive scan (pristine)
    int* sd  = (int*)(smem + kSdataOff);
    for (int i = t; i < kNCB; i += 256) h[i] = 0;
    __syncthreads();
    int base = blockIdx.x * kEPB;
    // pass 1: bucket counts
    #pragma unroll 4
    for (int j = 0; j < kEPB / 256; ++j) {
      int e = base + j * 256 + t;
      if (e < kTE) {
        int dst, boff;
        edge_bin(e, a0i, a1i, a2i, as0, as1, dst, boff);
        atomicAdd(&h[(boff + dst) >> 8], 1);
      }
    }
    __syncthreads();
    // emit counts, then exclusive-scan h -> loc (3 elems/thread)
    for (int i = t; i < kNCB; i += 256)
      G[(size_t)i * kNBA + blockIdx.x] = h[i];
    int i0 = t * 3;
    int a0 = (i0 < kNCB) ? h[i0] : 0;
    int a1 = (i0 + 1 < kNCB) ? h[i0 + 1] : 0;
    int a2 = (i0 + 2 < kNCB) ? h[i0 + 2] : 0;
    int ssum = a0 + a1 + a2;
    sd[t] = ssum;
    __syncthreads();
    for (int off = 1; off < 256; off <<= 1) {
      int x = (t >= off) ? sd[t - off] : 0;
      __syncthreads();
      sd[t] += x;
      __syncthreads();
    }
    int excl = sd[t] - ssum;
    if (i0 < kNCB)     loc[i0] = excl;
    if (i0 + 1 < kNCB) loc[i0 + 1] = excl + a0;
    if (i0 + 2 < kNCB) loc[i0 + 2] = excl + a0 + a1;
    __syncthreads();
    for (int i = t; i < kNCB; i += 256) {
      Loc[(size_t)i * kNBA + blockIdx.x] = loc[i];
      h[i] = loc[i];  // repurpose h as bump cursor
    }
    __syncthreads();
    // pass 2: decode again (L2-hot) and store DIRECTLY into the private
    // region, bucket-ordered. Scattered within 32KB -> lines L2-resident
    // until complete -> one writeback each.
    for (int j = 0; j < kEPB / 256; ++j) {
      int e = base + j * 256 + t;
      if (e < kTE) {
        int dst, src, boff; float val;
        edge_decode(e, a0i, a0v, a1i, a2i, as0, as1, dst, src, boff, val);
        int bin = boff + dst;
        int pos = atomicAdd(&h[bin >> 8], 1);  // LDS atomic
        stag[base + pos] = make_int2(src | ((bin & 255) << 24),
                                     __float_as_int(val));
      }
    }
    return;
  }
  // ---- gemm path: 32-row tile of Cb = bf16(A @ W), A[M,128], W[128,128] ----
  float* As = (float*)smem;
  int row0 = (blockIdx.x - kNBA) * kGemmRows;
  #pragma unroll
  for (int i = 0; i < 4; ++i) {
    int f = t + (i << 8);
    int r = f >> 5, c4 = (f & 31) << 2;
    int gr = row0 + r;
    float4 v = make_float4(0.f, 0.f, 0.f, 0.f);
    if (gr < M) v = *(const float4*)&A[(size_t)gr * 128 + c4];
    *(float4*)&As[r * 132 + c4] = v;
  }
  __syncthreads();
  int wcol = t & 31;
  int c4 = wcol << 2;
  int rsub = t >> 5;
  float4 acc[4];
  #pragma unroll
  for (int j = 0; j < 4; ++j) acc[j] = make_float4(0.f, 0.f, 0.f, 0.f);
  const float4* W4 = (const float4*)W;
  #pragma unroll 4
  for (int k = 0; k < 128; ++k) {
    float4 w = W4[k * 32 + wcol];
    #pragma unroll
    for (int j = 0; j < 4; ++j) {
      float a = As[(rsub + (j << 3)) * 132 + k];
      acc[j].x = fmaf(a, w.x, acc[j].x);
      acc[j].y = fmaf(a, w.y, acc[j].y);
      acc[j].z = fmaf(a, w.z, acc[j].z);
      acc[j].w = fmaf(a, w.w, acc[j].w);
    }
  }
  #pragma unroll
  for (int j = 0; j < 4; ++j) {
    int gr = row0 + rsub + (j << 3);
    if (gr < M) {
      ushort4 bb;
      bb.x = f2bf(acc[j].x); bb.y = f2bf(acc[j].y);
      bb.z = f2bf(acc[j].z); bb.w = f2bf(acc[j].w);
      *(ushort4*)&Cb[(size_t)gr * 128 + c4] = bb;
    }
  }
}

// 4096 elems/block, 16/thread, in-place safe (each thread reads its own 16
// elements into registers before any write).
__global__ __launch_bounds__(256) void scan1_kernel(
    const int* __restrict__ in, int* __restrict__ out,
    int* __restrict__ partials, int n) {
  __shared__ int sdata[256];
  int t = threadIdx.x;
  int base = blockIdx.x * kScanElems + t * 16;
  int v[16]; int s = 0;
  #pragma unroll
  for (int j = 0; j < 16; ++j) {
    int i = base + j;
    v[j] = (i < n) ? in[i] : 0;
    s += v[j];
  }
  sdata[t] = s;
  __syncthreads();
  for (int off = 1; off < 256; off <<= 1) {
    int x = (t >= off) ? sdata[t - off] : 0;
    __syncthreads();
    sdata[t] += x;
    __syncthreads();
  }
  int run = sdata[t] - s;
  #pragma unroll
  for (int j = 0; j < 16; ++j) {
    int i = base + j;
    if (i < n) out[i] = run;
    run += v[j];
  }
  if (t == 255) partials[blockIdx.x] = sdata[255];
}

__global__ __launch_bounds__(256) void scan2_kernel(int* partials, int nb) {
  __shared__ int sdata[256];
  int t = threadIdx.x;
  sdata[t] = (t < nb) ? partials[t] : 0;
  __syncthreads();
  for (int off = 1; off < 256; off <<= 1) {
    int x = (t >= off) ? sdata[t - off] : 0;
    __syncthreads();
    sdata[t] += x;
    __syncthreads();
  }
  if (t < nb) partials[t] = (t == 0) ? 0 : sdata[t - 1];
}

__global__ __launch_bounds__(256) void scan3_kernel(
    int* __restrict__ out, const int* __restrict__ partials, int n, int total) {
  int i = blockIdx.x * 256 + threadIdx.x;
  if (i < n) out[i] += partials[i >> 12];  // kScanElems = 2^12
  if (i == 0) out[n] = total;
}

// One block per coarse bucket; gathers the bucket's 544 fragments via LDS
// binary search, stages records in LDS, fine-sorts 256 bins.
// Block-uniform fallback (no LDS recs) if the bucket exceeds kCap.
__global__ __launch_bounds__(256) void finesort_kernel(
    const int* __restrict__ G, const int* __restrict__ Loc,
    const int2* __restrict__ stag, int* __restrict__ row_ptr,
    int2* __restrict__ edges) {
  __shared__ int2 recs[kCap];     // 34.8KB
  __shared__ int off[kNBA + 1];   // fragment offsets within bucket
  __shared__ int lrow[kNBA];      // fragment local offsets in block regions
  __shared__ int fcnt[kFB];
  __shared__ int fcur[kFB];
  int t = threadIdx.x;
  int b = blockIdx.x;
  int s = G[(size_t)b * kNBA];
  // G row and Loc row are contiguous; +1 fetches next bucket's start.
  for (int k = t; k < kNBA; k += 256) {
    off[k] = G[(size_t)b * kNBA + k] - s;
    lrow[k] = Loc[(size_t)b * kNBA + k];
  }
  if (t == 0) off[kNBA] = G[(size_t)(b + 1) * kNBA] - s;  // b=kNCB-1 -> G[kGN]=kTE
  fcnt[t] = 0;
  __syncthreads();
  int cnt = off[kNBA];
  if (cnt <= kCap) {
    for (int i = t; i < cnt; i += 256) {
      int lo = 0, hi = kNBA;  // off[lo] <= i < off[hi]
      while (hi - lo > 1) {
        int mid = (lo + hi) >> 1;
        if (off[mid] <= i) lo = mid; else hi = mid;
      }
      int2 r = stag[(size_t)lo * kEPB + lrow[lo] + (i - off[lo])];
      recs[i] = r;
      atomicAdd(&fcnt[((unsigned)r.x) >> 24], 1);
    }
    __syncthreads();
    int own = fcnt[t];
    for (int o = 1; o < kFB; o <<= 1) {
      int x = (t >= o) ? fcnt[t - o] : 0;
      __syncthreads();
      fcnt[t] += x;
      __syncthreads();
    }
    int excl = fcnt[t] - own;
    int bin = (b << 8) + t;
    if (bin < kTB) row_ptr[bin] = s + excl;
    if (b == 0 && t == 0) row_ptr[kTB] = kTE;
    fcur[t] = s + excl;
    __syncthreads();
    for (int i = t; i < cnt; i += 256) {
      int2 rec = recs[i];
      unsigned f = ((unsigned)rec.x) >> 24;
      int slot = atomicAdd(&fcur[f], 1);  // LDS atomic
      edges[slot] = make_int2(rec.x & 0x00FFFFFF, rec.y);
    }
  } else {
    // fallback: gather twice (binary search twice), no LDS recs
    for (int i = t; i < cnt; i += 256) {
      int lo = 0, hi = kNBA;
      while (hi - lo > 1) {
        int mid = (lo + hi) >> 1;
        if (off[mid] <= i) lo = mid; else hi = mid;
      }
      int2 r = stag[(size_t)lo * kEPB + lrow[lo] + (i - off[lo])];
      atomicAdd(&fcnt[((unsigned)r.x) >> 24], 1);
    }
    __syncthreads();
    int own = fcnt[t];
    for (int o = 1; o < kFB; o <<= 1) {
      int x = (t >= o) ? fcnt[t - o] : 0;
      __syncthreads();
      fcnt[t] += x;
      __syncthreads();
    }
    int excl = fcnt[t] - own;
    int bin = (b << 8) + t;
    if (bin < kTB) row_ptr[bin] = s + excl;
    if (b == 0 && t == 0) row_ptr[kTB] = kTE;
    fcur[t] = s + excl;
    __syncthreads();
    for (int i = t; i < cnt; i += 256) {
      int lo = 0, hi = kNBA;
      while (hi - lo > 1) {
        int mid = (lo + hi) >> 1;
        if (off[mid] <= i) lo = mid; else hi = mid;
      }
      int2 rec = stag[(size_t)lo * kEPB + lrow[lo] + (i - off[lo])];
      unsigned f = ((unsigned)rec.x) >> 24;
      int slot = atomicAdd(&fcur[f], 1);
      edges[slot] = make_int2(rec.x & 0x00FFFFFF, rec.y);
    }
  }
}

// Fused Q/K projection: one LDS tile of A, two K-loops (Wq -> fp32, Wk -> bf16).
__global__ __launch_bounds__(256) void gemm128_qk_kernel(
    const float* __restrict__ A, const float* __restrict__ Wq,
    const float* __restrict__ Wk, float* __restrict__ Qf,
    unsigned short* __restrict__ Kb, int M) {
  __shared__ float As[64 * 132];
  int t = threadIdx.x;
  int row0 = blockIdx.x << 6;
  #pragma unroll
  for (int i = 0; i < 8; ++i) {
    int f = t + (i << 8);
    int r = f >> 5, c4 = (f & 31) << 2;
    int gr = row0 + r;
    float4 v = make_float4(0.f, 0.f, 0.f, 0.f);
    if (gr < M) v = *(const float4*)&A[(size_t)gr * 128 + c4];
    *(float4*)&As[r * 132 + c4] = v;
  }
  __syncthreads();
  int wcol = t & 31;
  int c4 = wcol << 2;
  int rsub = t >> 5;
  float4 acc[8];
  const float4* Wq4 = (const float4*)Wq;
  const float4* Wk4 = (const float4*)Wk;
  #pragma unroll
  for (int j = 0; j < 8; ++j) acc[j] = make_float4(0.f, 0.f, 0.f, 0.f);
  #pragma unroll 4
  for (int k = 0; k < 128; ++k) {
    float4 w = Wq4[k * 32 + wcol];
    #pragma unroll
    for (int j = 0; j < 8; ++j) {
      float a = As[(rsub + (j << 3)) * 132 + k];
      acc[j].x = fmaf(a, w.x, acc[j].x);
      acc[j].y = fmaf(a, w.y, acc[j].y);
      acc[j].z = fmaf(a, w.z, acc[j].z);
      acc[j].w = fmaf(a, w.w, acc[j].w);
    }
  }
  #pragma unroll
  for (int j = 0; j < 8; ++j) {
    int gr = row0 + rsub + (j << 3);
    if (gr < M) *(float4*)&Qf[(size_t)gr * 128 + c4] = acc[j];
  }
  #pragma unroll
  for (int j = 0; j < 8; ++j) acc[j] = make_float4(0.f, 0.f, 0.f, 0.f);
  #pragma unroll 4
  for (int k = 0; k < 128; ++k) {
    float4 w = Wk4[k * 32 + wcol];
    #pragma unroll
    for (int j = 0; j < 8; ++j) {
      float a = As[(rsub + (j << 3)) * 132 + k];
      acc[j].x = fmaf(a, w.x, acc[j].x);
      acc[j].y = fmaf(a, w.y, acc[j].y);
      acc[j].z = fmaf(a, w.z, acc[j].z);
      acc[j].w = fmaf(a, w.w, acc[j].w);
    }
  }
  #pragma unroll
  for (int j = 0; j < 8; ++j) {
    int gr = row0 + rsub + (j << 3);
    if (gr < M) {
      ushort4 b;
      b.x = f2bf(acc[j].x); b.y = f2bf(acc[j].y);
      b.z = f2bf(acc[j].z); b.w = f2bf(acc[j].w);
      *(ushort4*)&Kb[(size_t)gr * 128 + c4] = b;
    }
  }
}

// Fused double-unpool + gc2 projection:
//   crf_row[r] = H2[assign1[assign0[r]]] + H1[assign0[r]] + Gcn[r]
//   crf_h[r]   = crf_row (output), Cb[r] = bf16(crf_row @ W2)
__global__ __launch_bounds__(256) void unpool_gemm40_kernel(
    const float* __restrict__ H2, const float* __restrict__ H1,
    const float* __restrict__ Gcn, const int* __restrict__ assign0,
    const int* __restrict__ assign1, const float* __restrict__ W,
    float* __restrict__ crf_out, unsigned short* __restrict__ Cb, int M) {
  __shared__ float Ws[128 * 40];
  __shared__ float As[64 * 132];
  __shared__ int ia0[64], ia1[64];
  int t = threadIdx.x;
  int row0 = blockIdx.x << 6;
  #pragma unroll
  for (int i = 0; i < 5; ++i)
    ((float4*)Ws)[t + i * 256] = ((const float4*)W)[t + i * 256];
  if (t < 64) {
    int gr = row0 + t;
    int a0 = (gr < M) ? assign0[gr] : 0;
    ia0[t] = a0;
    ia1[t] = assign1[a0];
  }
  __syncthreads();
  #pragma unroll
  for (int i = 0; i < 8; ++i) {
    int f = t + (i << 8);
    int r = f >> 5, c4 = (f & 31) << 2;
    int gr = row0 + r;
    float4 v = make_float4(0.f, 0.f, 0.f, 0.f);
    if (gr < M) {
      float4 v2 = *(const float4*)&H2[(size_t)ia1[r] * 128 + c4];
      float4 v1 = *(const float4*)&H1[(size_t)ia0[r] * 128 + c4];
      float4 vg = *(const float4*)&Gcn[(size_t)gr * 128 + c4];
      v = make_float4(v2.x + v1.x + vg.x, v2.y + v1.y + vg.y,
                      v2.z + v1.z + vg.z, v2.w + v1.w + vg.w);
      *(float4*)&crf_out[(size_t)gr * 128 + c4] = v;
    }
    *(float4*)&As[r * 132 + c4] = v;
  }
  __syncthreads();
  int r = t >> 2;
  int cg = (t & 3) * 10;
  float acc[10];
  #pragma unroll
  for (int j = 0; j < 10; ++j) acc[j] = 0.f;
  for (int k = 0; k < 128; ++k) {
    float a = As[r * 132 + k];
    #pragma unroll
    for (int j = 0; j < 10; ++j) acc[j] = fmaf(a, Ws[k * 40 + cg + j], acc[j]);
  }
  int gr = row0 + r;
  if (gr < M) {
    #pragma unroll
    for (int j = 0; j < 10; ++j) Cb[(size_t)gr * 40 + cg + j] = f2bf(acc[j]);
  }
}

// ---------------------------------------------------------------------------
// Pull-SpMM over CSR: one wave per dst row, 128 cols (2/lane), 4-way MLP.
// ---------------------------------------------------------------------------
template <bool BF16>
__global__ __launch_bounds__(256) void spmm128_kernel(
    const int* __restrict__ row_ptr, const int2* __restrict__ edges,
    const void* __restrict__ Xv, float* __restrict__ Y,
    const float* __restrict__ bias, int nrows, int do_relu) {
  int wid = (blockIdx.x * 256 + threadIdx.x) >> 6;
  int lane = threadIdx.x & 63;
  if (wid >= nrows) return;
  int start = row_ptr[wid], end = row_ptr[wid + 1];
  const unsigned short* Xb = (const unsigned short*)Xv;
  const float* Xf = (const float*)Xv;
  float2 accA = make_float2(0.f, 0.f), accB = make_float2(0.f, 0.f);
  for (int base = start; base < end; base += 64) {
    int cnt = end - base; if (cnt > 64) cnt = 64;
    int2 e_l = make_int2(0, 0);
    if (lane < cnt) e_l = edges[base + lane];
    int j = 0;
    for (; j + 4 <= cnt; j += 4) {
      int s0 = __shfl(e_l.x, j + 0), s1 = __shfl(e_l.x, j + 1);
      int s2 = __shfl(e_l.x, j + 2), s3 = __shfl(e_l.x, j + 3);
      float v0 = __int_as_float(__shfl(e_l.y, j + 0));
      float v1 = __int_as_float(__shfl(e_l.y, j + 1));
      float v2 = __int_as_float(__shfl(e_l.y, j + 2));
      float v3 = __int_as_float(__shfl(e_l.y, j + 3));
      if (BF16) {
        unsigned int u0 = *(const unsigned int*)(Xb + (size_t)s0 * 128 + lane * 2);
        unsigned int u1 = *(const unsigned int*)(Xb + (size_t)s1 * 128 + lane * 2);
        unsigned int u2 = *(const unsigned int*)(Xb + (size_t)s2 * 128 + lane * 2);
        unsigned int u3 = *(const unsigned int*)(Xb + (size_t)s3 * 128 + lane * 2);
        accA.x = fmaf(v0, bf_lo(u0), accA.x); accA.y = fmaf(v0, bf_hi(u0), accA.y);
        accB.x = fmaf(v1, bf_lo(u1), accB.x); accB.y = fmaf(v1, bf_hi(u1), accB.y);
        accA.x = fmaf(v2, bf_lo(u2), accA.x); accA.y = fmaf(v2, bf_hi(u2), accA.y);
        accB.x = fmaf(v3, bf_lo(u3), accB.x); accB.y = fmaf(v3, bf_hi(u3), accB.y);
      } else {
        float2 x0 = *(const float2*)(Xf + (size_t)s0 * 128 + lane * 2);
        float2 x1 = *(const float2*)(Xf + (size_t)s1 * 128 + lane * 2);
        float2 x2 = *(const float2*)(Xf + (size_t)s2 * 128 + lane * 2);
        float2 x3 = *(const float2*)(Xf + (size_t)s3 * 128 + lane * 2);
        accA.x = fmaf(v0, x0.x, accA.x); accA.y = fmaf(v0, x0.y, accA.y);
        accB.x = fmaf(v1, x1.x, accB.x); accB.y = fmaf(v1, x1.y, accB.y);
        accA.x = fmaf(v2, x2.x, accA.x); accA.y = fmaf(v2, x2.y, accA.y);
        accB.x = fmaf(v3, x3.x, accB.x); accB.y = fmaf(v3, x3.y, accB.y);
      }
    }
    for (; j < cnt; ++j) {
      int src = __shfl(e_l.x, j);
      float val = __int_as_float(__shfl(e_l.y, j));
      if (BF16) {
        unsigned int u = *(const unsigned int*)(Xb + (size_t)src * 128 + lane * 2);
        accA.x = fmaf(val, bf_lo(u), accA.x);
        accA.y = fmaf(val, bf_hi(u), accA.y);
      } else {
        float2 xv = *(const float2*)(Xf + (size_t)src * 128 + lane * 2);
        accA.x = fmaf(val, xv.x, accA.x);
        accA.y = fmaf(val, xv.y, accA.y);
      }
    }
  }
  float2 acc = make_float2(accA.x + accB.x, accA.y + accB.y);
  if (bias) { acc.x += bias[lane * 2]; acc.y += bias[lane * 2 + 1]; }
  if (do_relu) { acc.x = fmaxf(acc.x, 0.f); acc.y = fmaxf(acc.y, 0.f); }
  *(float2*)&Y[(size_t)wid * 128 + lane * 2] = acc;
}

// Pool (T-graph pull sum) fused with nwgt-embedding add, 4-way MLP.
__global__ __launch_bounds__(256) void pool_emb_kernel(
    const int* __restrict__ row_ptr, const int2* __restrict__ edges,
    const float* __restrict__ X, const int* __restrict__ nwgt,
    const float* __restrict__ emb, float* __restrict__ Hpool,
    float* __restrict__ H0, unsigned short* __restrict__ H0b, int nrows) {
  int wid = (blockIdx.x * 256 + threadIdx.x) >> 6;
  int lane = threadIdx.x & 63;
  if (wid >= nrows) return;
  int start = row_ptr[wid], end = row_ptr[wid + 1];
  float2 accA = make_float2(0.f, 0.f), accB = make_float2(0.f, 0.f);
  for (int base = start; base < end; base += 64) {
    int cnt = end - base; if (cnt > 64) cnt = 64;
    int s_l = 0;
    if (lane < cnt) s_l = edges[base + lane].x;
    int j = 0;
    for (; j + 4 <= cnt; j += 4) {
      int s0 = __shfl(s_l, j + 0), s1 = __shfl(s_l, j + 1);
      int s2 = __shfl(s_l, j + 2), s3 = __shfl(s_l, j + 3);
      float2 x0 = *(const float2*)&X[(size_t)s0 * 128 + lane * 2];
      float2 x1 = *(const float2*)&X[(size_t)s1 * 128 + lane * 2];
      float2 x2 = *(const float2*)&X[(size_t)s2 * 128 + lane * 2];
      float2 x3 = *(const float2*)&X[(size_t)s3 * 128 + lane * 2];
      accA.x += x0.x + x2.x; accA.y += x0.y + x2.y;
      accB.x += x1.x + x3.x; accB.y += x1.y + x3.y;
    }
    for (; j < cnt; ++j) {
      int src = __shfl(s_l, j);
      float2 xv = *(const float2*)&X[(size_t)src * 128 + lane * 2];
      accA.x += xv.x; accA.y += xv.y;
    }
  }
  float2 acc = make_float2(accA.x + accB.x, accA.y + accB.y);
  *(float2*)&Hpool[(size_t)wid * 128 + lane * 2] = acc;
  float2 ev = *(const float2*)&emb[(size_t)nwgt[wid] * 128 + lane * 2];
  float2 h0 = make_float2(acc.x + ev.x, acc.y + ev.y);
  *(float2*)&H0[(size_t)wid * 128 + lane * 2] = h0;
  unsigned int packed = ((unsigned int)f2bf(h0.x)) | (((unsigned int)f2bf(h0.y)) << 16);
  *(unsigned int*)(H0b + (size_t)wid * 128 + lane * 2) = packed;
}

__global__ __launch_bounds__(256) void spmm40_kernel(
    const int* __restrict__ row_ptr, const int2* __restrict__ edges,
    const unsigned short* __restrict__ Xb, float* __restrict__ Y,
    const float* __restrict__ bias, int nrows) {
  int wid = (blockIdx.x * 256 + threadIdx.x) >> 6;
  int lane = threadIdx.x & 63;
  if (wid >= nrows) return;
  int start = row_ptr[wid], end = row_ptr[wid + 1];
  float accA = 0.f, accB = 0.f;
  for (int base = start; base < end; base += 64) {
    int cnt = end - base; if (cnt > 64) cnt = 64;
    int2 e_l = make_int2(0, 0);
    if (lane < cnt) e_l = edges[base + lane];
    int j = 0;
    for (; j + 4 <= cnt; j += 4) {
      int s0 = __shfl(e_l.x, j + 0), s1 = __shfl(e_l.x, j + 1);
      int s2 = __shfl(e_l.x, j + 2), s3 = __shfl(e_l.x, j + 3);
      float v0 = __int_as_float(__shfl(e_l.y, j + 0));
      float v1 = __int_as_float(__shfl(e_l.y, j + 1));
      float v2 = __int_as_float(__shfl(e_l.y, j + 2));
      float v3 = __int_as_float(__shfl(e_l.y, j + 3));
      if (lane < 40) {
        unsigned short u0 = Xb[(size_t)s0 * 40 + lane];
        unsigned short u1 = Xb[(size_t)s1 * 40 + lane];
        unsigned short u2 = Xb[(size_t)s2 * 40 + lane];
        unsigned short u3 = Xb[(size_t)s3 * 40 + lane];
        accA = fmaf(v0, __uint_as_float(((unsigned int)u0) << 16), accA);
        accB = fmaf(v1, __uint_as_float(((unsigned int)u1) << 16), accB);
        accA = fmaf(v2, __uint_as_float(((unsigned int)u2) << 16), accA);
        accB = fmaf(v3, __uint_as_float(((unsigned int)u3) << 16), accB);
      }
    }
    for (; j < cnt; ++j) {
      int src = __shfl(e_l.x, j);
      float val = __int_as_float(__shfl(e_l.y, j));
      if (lane < 40) {
        unsigned short u = Xb[(size_t)src * 40 + lane];
        accA = fmaf(val, __uint_as_float(((unsigned int)u) << 16), accA);
      }
    }
  }
  if (lane < 40) Y[(size_t)wid * 40 + lane] = accA + accB + bias[lane];
}

// ---------------------------------------------------------------------------
// Fused CRF row kernel, 4 edges per step: batched k/h0 gathers (8 loads in
// flight), 4 interleaved butterfly dot-reductions, one online-softmax update.
// ---------------------------------------------------------------------------
__global__ __launch_bounds__(256) void crf_fused_kernel(
    const int* __restrict__ row_ptr, const int2* __restrict__ edges,
    const float* __restrict__ Q, const unsigned short* __restrict__ Kb,
    const float* __restrict__ H0, const unsigned short* __restrict__ H0b,
    float* __restrict__ Y, const float* __restrict__ alpha_p,
    const float* __restrict__ beta_p, int nrows) {
  int wid = (blockIdx.x * 256 + threadIdx.x) >> 6;
  int lane = threadIdx.x & 63;
  if (wid >= nrows) return;
  int start = row_ptr[wid], end = row_ptr[wid + 1];
  float2 qv = *(const float2*)&Q[(size_t)wid * 128 + lane * 2];
  const float kScale = 0.08838834764831845f;  // 1/sqrt(128)
  float m = -3.4e38f, z = 0.f;
  float2 msg = make_float2(0.f, 0.f);
  for (int base = start; base < end; base += 64) {
    int cnt = end - base; if (cnt > 64) cnt = 64;
    int s_l = 0;
    if (lane < cnt) s_l = edges[base + lane].x;
    int j = 0;
    for (; j + 4 <= cnt; j += 4) {
      int s0 = __shfl(s_l, j + 0), s1 = __shfl(s_l, j + 1);
      int s2 = __shfl(s_l, j + 2), s3 = __shfl(s_l, j + 3);
      unsigned int k0 = *(const unsigned int*)(Kb + (size_t)s0 * 128 + lane * 2);
      unsigned int k1 = *(const unsigned int*)(Kb + (size_t)s1 * 128 + lane * 2);
      unsigned int k2 = *(const unsigned int*)(Kb + (size_t)s2 * 128 + lane * 2);
      unsigned int k3 = *(const unsigned int*)(Kb + (size_t)s3 * 128 + lane * 2);
      unsigned int h0 = *(const unsigned int*)(H0b + (size_t)s0 * 128 + lane * 2);
      unsigned int h1 = *(const unsigned int*)(H0b + (size_t)s1 * 128 + lane * 2);
      unsigned int h2 = *(const unsigned int*)(H0b + (size_t)s2 * 128 + lane * 2);
      unsigned int h3 = *(const unsigned int*)(H0b + (size_t)s3 * 128 + lane * 2);
      float p0 = qv.x * bf_lo(k0) + qv.y * bf_hi(k0);
      float p1 = qv.x * bf_lo(k1) + qv.y * bf_hi(k1);
      float p2 = qv.x * bf_lo(k2) + qv.y * bf_hi(k2);
      float p3 = qv.x * bf_lo(k3) + qv.y * bf_hi(k3);
      #pragma unroll
      for (int d = 32; d >= 1; d >>= 1) {
        p0 += __shfl_xor(p0, d);
        p1 += __shfl_xor(p1, d);
        p2 += __shfl_xor(p2, d);
        p3 += __shfl_xor(p3, d);
      }
      p0 *= kScale; p1 *= kScale; p2 *= kScale; p3 *= kScale;
      float pm = fmaxf(fmaxf(p0, p1), fmaxf(p2, p3));
      float mn = fmaxf(m, pm);
      float corr = __expf(m - mn);
      float w0 = __expf(p0 - mn), w1 = __expf(p1 - mn);
      float w2 = __expf(p2 - mn), w3 = __expf(p3 - mn);
      z = z * corr + (w0 + w1) + (w2 + w3);
      msg.x = msg.x * corr + w0 * bf_lo(h0) + w1 * bf_lo(h1)
                           + w2 * bf_lo(h2) + w3 * bf_lo(h3);
      msg.y = msg.y * corr + w0 * bf_hi(h0) + w1 * bf_hi(h1)
                           + w2 * bf_hi(h2) + w3 * bf_hi(h3);
      m = mn;
    }
    for (; j < cnt; ++j) {
      int src = __shfl(s_l, j);
      unsigned int ku = *(const unsigned int*)(Kb + (size_t)src * 128 + lane * 2);
      unsigned int hu = *(const unsigned int*)(H0b + (size_t)src * 128 + lane * 2);
      float p = qv.x * bf_lo(ku) + qv.y * bf_hi(ku);
      #pragma unroll
      for (int d = 32; d >= 1; d >>= 1) p += __shfl_xor(p, d);
      p *= kScale;
      float mn = fmaxf(m, p);
      float corr = __expf(m - mn);
      float w = __expf(p - mn);
      z = z * corr + w;
      msg.x = msg.x * corr + w * bf_lo(hu);
      msg.y = msg.y * corr + w * bf_hi(hu);
      m = mn;
    }
  }
  float alpha = *alpha_p, beta = *beta_p;
  float inv = 1.0f / (z + 1e-16f);
  float2 h0i = *(const float2*)&H0[(size_t)wid * 128 + lane * 2];
  float sc = 1.0f / (alpha + beta);
  float2 o;
  o.x = (alpha * h0i.x + beta * (msg.x * inv)) * sc;
  o.y = (alpha * h0i.y + beta * (msg.y * inv)) * sc;
  *(float2*)&Y[(size_t)wid * 128 + lane * 2] = o;
}

}  // namespace

// ---------------------------------------------------------------------------
extern "C" void kernel_launch(void* const* d_in, const int* in_sizes, int n_in,
                              void* d_out, int out_size, void* d_ws, size_t ws_size,
                              hipStream_t stream) {
  const float* x       = (const float*)d_in[0];
  const int*   A0_idx  = (const int*)d_in[1];
  const float* A0_val  = (const float*)d_in[2];
  const int*   A1_idx  = (const int*)d_in[3];
  const int*   A2_idx  = (const int*)d_in[5];
  const int*   assign0 = (const int*)d_in[7];
  const int*   assign1 = (const int*)d_in[8];
  const int*   nwgt1   = (const int*)d_in[9];
  const int*   nwgt2   = (const int*)d_in[10];
  const float* gc1_W   = (const float*)d_in[11];
  const float* gc1_b   = (const float*)d_in[12];
  const float* gc2_W   = (const float*)d_in[13];
  const float* gc2_b   = (const float*)d_in[14];
  const float* c1_Wq   = (const float*)d_in[15];
  const float* c1_Wk   = (const float*)d_in[16];
  const float* c1_emb  = (const float*)d_in[17];
  const float* c1_al   = (const float*)d_in[18];
  const float* c1_be   = (const float*)d_in[19];
  const float* c2_Wq   = (const float*)d_in[20];
  const float* c2_Wk   = (const float*)d_in[21];
  const float* c2_emb  = (const float*)d_in[22];
  const float* c2_al   = (const float*)d_in[23];
  const float* c2_be   = (const float*)d_in[24];

  float* out_g = (float*)d_out;                      // [N0, 40]
  float* gcn_h = out_g + (size_t)kN0 * 40;           // [N0, 128]
  float* crf_h = gcn_h + (size_t)kN0 * 128;          // [N0, 128]

  // ---- workspace carving ----
  char* ws = (char*)d_ws;
  size_t off = 0;
  auto carve = [&](size_t bytes) -> void* {
    void* p = ws + off;
    off += (bytes + 511) & ~(size_t)511;
    return p;
  };
  int*   G        = (int*)carve((size_t)(kGN + 1) * 4);    // 1.38 MB bucket matrix
  int*   Loc      = (int*)carve((size_t)kGN * 4);          // 1.38 MB local offsets
  int*   row_ptr  = (int*)carve((size_t)(kTB + 1) * 4);
  int*   partials = (int*)carve(1024);
  int2*  edges    = (int2*)carve((size_t)kTE * 8);         // 17.8 MB
  float* h1_crf   = (float*)carve((size_t)kN1 * 128 * 4);  // 12.8 MB, long-lived
  char*  arena    = (char*)carve(51200000 + 4096);         // reused overlays
  // Overlays (byte offsets; lifetimes vs launch order):
  unsigned short* xWb   = (unsigned short*)(arena);              // [sortblk-gemm .. gc1 spmm]
  int2* stag_rec = (int2*)(arena + 25600000);                    // [sortblk .. finesort], 544*4096*8=17.8MB
  float* h1_pool = (float*)(arena);                              // [pool1 .. qk1]
  float* h0_1    = (float*)(arena + 12800000);                   // [pool1 .. crf1]
  unsigned short* h0_1b = (unsigned short*)(arena + 25600000);   // [pool1 .. crf1]
  float* q1      = (float*)(arena + 32000000);                   // [qk1 .. crf1]
  unsigned short* k1b   = (unsigned short*)(arena + 44800000);   // [qk1 .. crf1]
  float* h2_pool = (float*)(arena);                              // [pool2 .. qk2]
  float* h0_2    = (float*)(arena + 3200000);                    // [pool2 .. crf2]
  unsigned short* h0_2b = (unsigned short*)(arena + 6400000);    // [pool2 .. crf2]
  float* q2      = (float*)(arena + 8000000);                    // [qk2 .. crf2]
  unsigned short* k2b   = (unsigned short*)(arena + 11200000);   // [qk2 .. crf2]
  float* h2_crf  = (float*)(arena + 12800000);                   // [crf2 .. unpool]
  unsigned short* hW2b  = (unsigned short*)(arena);              // [unpool_gemm40 .. spmm40]
  // stag_rec [25.6M,43.45M) is disjoint from xWb [0,25.6M) during the
  // sortblk+gemm / finesort dispatches and dead before pool1 writes h0_1b.

  // ---- 1. CSR build: sortblk(+gc1 gemm) -> scan(G) -> finesort ----
  sortblk_gemm_kernel<<<kNBA + kGemmBlocks, 256, 0, stream>>>(
      A0_idx, A0_val, A1_idx, A2_idx, assign0, assign1, G, Loc, stag_rec,
      x, gc1_W, xWb, kN0);
  scan1_kernel<<<kNBLK_G, 256, 0, stream>>>(G, G, partials, kGN);
  scan2_kernel<<<1, 256, 0, stream>>>(partials, kNBLK_G);
  scan3_kernel<<<(kGN + 255) / 256, 256, 0, stream>>>(G, partials, kGN, kTE);
  finesort_kernel<<<kNCB, 256, 0, stream>>>(G, Loc, stag_rec, row_ptr, edges);

  // ---- 2. gc1 aggregation: h = relu(A0 @ (x W1) + b1) -> gcn_hidden ----
  spmm128_kernel<true><<<(kN0 + 3) / 4, 256, 0, stream>>>(row_ptr, edges, xWb,
                                                          gcn_h, gc1_b, kN0, 1);
  // ---- 3. level-1 pool(+emb) + QK + CRF ----
  pool_emb_kernel<<<(kN1 + 3) / 4, 256, 0, stream>>>(row_ptr + kBO3, edges, gcn_h,
                                                     nwgt1, c1_emb, h1_pool, h0_1,
                                                     h0_1b, kN1);
  gemm128_qk_kernel<<<(kN1 + 63) / 64, 256, 0, stream>>>(h1_pool, c1_Wq, c1_Wk,
                                                         q1, k1b, kN1);
  crf_fused_kernel<<<(kN1 + 3) / 4, 256, 0, stream>>>(row_ptr + kBO1, edges, q1, k1b,
                                                      h0_1, h0_1b, h1_crf, c1_al,
                                                      c1_be, kN1);
  // ---- 4. level-2 pool(+emb) + QK + CRF ----
  pool_emb_kernel<<<(kN2 + 3) / 4, 256, 0, stream>>>(row_ptr + kBO4, edges, h1_crf,
                                                     nwgt2, c2_emb, h2_pool, h0_2,
                                                     h0_2b, kN2);
  gemm128_qk_kernel<<<(kN2 + 63) / 64, 256, 0, stream>>>(h2_pool, c2_Wq, c2_Wk,
                                                         q2, k2b, kN2);
  crf_fused_kernel<<<(kN2 + 3) / 4, 256, 0, stream>>>(row_ptr + kBO2, edges, q2, k2b,
                                                      h0_2, h0_2b, h2_crf, c2_al,
                                                      c2_be, kN2);
  // ---- 5+6. fused double unpool -> crf_hidden, + gc2 projection (bf16) ----
  unpool_gemm40_kernel<<<(kN0 + 63) / 64, 256, 0, stream>>>(
      h2_crf, h1_crf, gcn_h, assign0, assign1, gc2_W, crf_h, hW2b, kN0);
  spmm40_kernel<<<(kN0 + 3) / 4, 256, 0, stream>>>(row_ptr, edges, hW2b,
                                                   out_g, gc2_b, kN0);
}

// Round 10
// 638.097 us; speedup vs baseline: 1.0181x; 1.0181x over previous
//
#include <hip/hip_runtime.h>
#include <hip/hip_bf16.h>
#include <math.h>

namespace {

constexpr int kN0 = 100000, kN1 = 25000, kN2 = 6250;
constexpr int kE0 = 1600000, kE1 = 400000, kE2 = 100000;
// Concatenated-edge layout: [A0 | A1 | A2 | T0(assign0) | T1(assign1)]
constexpr int kEO1 = kE0;                   // 1,600,000
constexpr int kEO2 = kEO1 + kE1;            // 2,000,000
constexpr int kEO3 = kEO2 + kE2;            // 2,100,000
constexpr int kEO4 = kEO3 + kN0;            // 2,200,000
constexpr int kTE  = kEO4 + kN1;            // 2,225,000
// Concatenated-bin layout (destination node counts per graph)
constexpr int kBO1 = kN0;                   // A1 bins
constexpr int kBO2 = kBO1 + kN1;            // A2 bins
constexpr int kBO3 = kBO2 + kN2;            // T0 bins
constexpr int kBO4 = kBO3 + kN1;            // T1 bins
constexpr int kTB  = kBO4 + kN2;            // 162,500 total bins

// ---- two-level bucket sort geometry ----
// r10 = r8 structure (LDS-staged recs -> write-once coalesced stag region;
// r9 showed direct scatter re-dirties L2 lines: 288 live 32KB regions/XCD
// > 4MB L2 -> WRITE 64->94MB) + register-cached decode: each thread decodes
// its 16 edges ONCE into VGPRs (pass 2 places from registers), removing the
// second 23.7MB edge-read pass and its latency chain.
constexpr int kFB  = 256;                   // fine bins per bucket
constexpr int kNCB = (kTB + kFB - 1) / kFB; // 635 coarse buckets
constexpr int kEPB = 4096;                  // edges per sortblk block
constexpr int kEPT = kEPB / 256;            // 16 edges per thread
constexpr int kNBA = (kTE + kEPB - 1) / kEPB;  // 544 blocks
constexpr int kGN  = kNCB * kNBA;           // 345,440 (bucket-major G matrix)
constexpr int kScanElems = 4096;            // elems per scan1 block (16/thread)
constexpr int kNBLK_G = (kGN + kScanElems - 1) / kScanElems;  // 85 (<=256 ok)

// Bucket record cap for LDS staging in finesort: avg bucket = 4096 edges,
// sigma ~ 64 (multinomial) -> 4352 = avg + 4 sigma. Fallback path if bigger.
constexpr int kCap = 4352;                  // 34.8KB of int2 in LDS

constexpr int kGemmRows = 32;               // fused gemm tile rows (256 thr)
constexpr int kGemmBlocks = (kN0 + kGemmRows - 1) / kGemmRows;  // 3,125

// sortblk LDS union layout (bytes): sort path 38,872 / gemm path 16,896.
constexpr int kRecsOff  = 0;                // int2[4096]  = 32768
constexpr int kHOff     = 32768;            // int[635]    = 2540
constexpr int kLocOff   = 35308;            // int[635]    = 2540
constexpr int kSdataOff = 37848;            // int[256]    = 1024
constexpr int kSmemSz   = 38872;

__device__ __forceinline__ float bf_lo(unsigned int u) {
  return __uint_as_float(u << 16);
}
__device__ __forceinline__ float bf_hi(unsigned int u) {
  return __uint_as_float(u & 0xffff0000u);
}
__device__ __forceinline__ unsigned short f2bf(float f) {
  __hip_bfloat16 h = __float2bfloat16(f);
  return *reinterpret_cast<unsigned short*>(&h);
}

__device__ __forceinline__ void edge_decode(
    int t, const int* a0i, const float* a0v, const int* a1i, const int* a2i,
    const int* as0, const int* as1, int& dst, int& src, int& boff, float& val) {
  if (t < kEO1)      { dst = a0i[t]; src = a0i[kE0 + t]; val = a0v[t]; boff = 0; }
  else if (t < kEO2) { int e = t - kEO1; dst = a1i[e]; src = a1i[kE1 + e]; val = 1.0f; boff = kBO1; }
  else if (t < kEO3) { int e = t - kEO2; dst = a2i[e]; src = a2i[kE2 + e]; val = 1.0f; boff = kBO2; }
  else if (t < kEO4) { int e = t - kEO3; dst = as0[e]; src = e;            val = 1.0f; boff = kBO3; }
  else               { int e = t - kEO4; dst = as1[e]; src = e;            val = 1.0f; boff = kBO4; }
}

// ---------------------------------------------------------------------------
// CSR build via two-level bucket sort — ZERO global atomics:
//  sortblk: decode 16 edges/thread ONCE into registers while building the
//           LDS bucket histogram; LDS scan; place from registers into the
//           LDS recs buffer (bucket-ordered); stream the block's private
//           32KB stag region out coalesced (write-once). Emits G counts +
//           Loc local offsets. gc1 GEMM blocks ride along.
//  scan:    exclusive scan of G (bucket-major): Gs[b][k]-Gs[b][0] = fragment
//           offset of block k within bucket b; Gs[b][0] = bucket start.
//  finesort: one block per bucket; gathers its 544 fragments via LDS binary
//           search over the (contiguous) G/Loc rows, stages in LDS, then
//           fine-sorts 256 bins -> row_ptr + final edges.
// ---------------------------------------------------------------------------

__global__ __launch_bounds__(256) void sortblk_gemm_kernel(
    const int* __restrict__ a0i, const float* __restrict__ a0v,
    const int* __restrict__ a1i, const int* __restrict__ a2i,
    const int* __restrict__ as0, const int* __restrict__ as1,
    int* __restrict__ G, int* __restrict__ Loc, int2* __restrict__ stag,
    const float* __restrict__ A, const float* __restrict__ W,
    unsigned short* __restrict__ Cb, int M) {
  __shared__ __align__(16) unsigned char smem[kSmemSz];
  int t = threadIdx.x;
  if (blockIdx.x < kNBA) {
    int2* recs = (int2*)(smem + kRecsOff);
    int*  h    = (int*)(smem + kHOff);     // counts, then bump cursors
    int*  loc  = (int*)(smem + kLocOff);   // exclusive scan (pristine)
    int*  sd   = (int*)(smem + kSdataOff);
    for (int i = t; i < kNCB; i += 256) h[i] = 0;
    __syncthreads();
    int base = blockIdx.x * kEPB;
    int n = kTE - base; if (n > kEPB) n = kEPB;
    // pass 1: decode ONCE into registers + LDS bucket counts
    int rbkt[kEPT]; int rx[kEPT]; int ry[kEPT];
    #pragma unroll
    for (int j = 0; j < kEPT; ++j) {
      int e = base + j * 256 + t;
      rbkt[j] = -1;
      if (e < kTE) {
        int dst, src, boff; float val;
        edge_decode(e, a0i, a0v, a1i, a2i, as0, as1, dst, src, boff, val);
        int bin = boff + dst;
        rbkt[j] = bin >> 8;
        rx[j] = src | ((bin & 255) << 24);  // src < 2^24
        ry[j] = __float_as_int(val);
        atomicAdd(&h[bin >> 8], 1);
      }
    }
    __syncthreads();
    // emit counts, then exclusive-scan h -> loc (3 elems/thread)
    for (int i = t; i < kNCB; i += 256)
      G[(size_t)i * kNBA + blockIdx.x] = h[i];
    int i0 = t * 3;
    int a0 = (i0 < kNCB) ? h[i0] : 0;
    int a1 = (i0 + 1 < kNCB) ? h[i0 + 1] : 0;
    int a2 = (i0 + 2 < kNCB) ? h[i0 + 2] : 0;
    int ssum = a0 + a1 + a2;
    sd[t] = ssum;
    __syncthreads();
    for (int off = 1; off < 256; off <<= 1) {
      int x = (t >= off) ? sd[t - off] : 0;
      __syncthreads();
      sd[t] += x;
      __syncthreads();
    }
    int excl = sd[t] - ssum;
    if (i0 < kNCB)     loc[i0] = excl;
    if (i0 + 1 < kNCB) loc[i0 + 1] = excl + a0;
    if (i0 + 2 < kNCB) loc[i0 + 2] = excl + a0 + a1;
    __syncthreads();
    for (int i = t; i < kNCB; i += 256) {
      Loc[(size_t)i * kNBA + blockIdx.x] = loc[i];
      h[i] = loc[i];  // repurpose h as bump cursor
    }
    __syncthreads();
    // pass 2: place from REGISTERS into LDS, bucket-ordered
    #pragma unroll
    for (int j = 0; j < kEPT; ++j) {
      if (rbkt[j] >= 0) {
        int pos = atomicAdd(&h[rbkt[j]], 1);  // LDS atomic
        recs[pos] = make_int2(rx[j], ry[j]);
      }
    }
    __syncthreads();
    // write-once, coalesced region store
    for (int i = t; i < n; i += 256) stag[base + i] = recs[i];
    return;
  }
  // ---- gemm path: 32-row tile of Cb = bf16(A @ W), A[M,128], W[128,128] ----
  float* As = (float*)smem;
  int row0 = (blockIdx.x - kNBA) * kGemmRows;
  #pragma unroll
  for (int i = 0; i < 4; ++i) {
    int f = t + (i << 8);
    int r = f >> 5, c4 = (f & 31) << 2;
    int gr = row0 + r;
    float4 v = make_float4(0.f, 0.f, 0.f, 0.f);
    if (gr < M) v = *(const float4*)&A[(size_t)gr * 128 + c4];
    *(float4*)&As[r * 132 + c4] = v;
  }
  __syncthreads();
  int wcol = t & 31;
  int c4 = wcol << 2;
  int rsub = t >> 5;
  float4 acc[4];
  #pragma unroll
  for (int j = 0; j < 4; ++j) acc[j] = make_float4(0.f, 0.f, 0.f, 0.f);
  const float4* W4 = (const float4*)W;
  #pragma unroll 4
  for (int k = 0; k < 128; ++k) {
    float4 w = W4[k * 32 + wcol];
    #pragma unroll
    for (int j = 0; j < 4; ++j) {
      float a = As[(rsub + (j << 3)) * 132 + k];
      acc[j].x = fmaf(a, w.x, acc[j].x);
      acc[j].y = fmaf(a, w.y, acc[j].y);
      acc[j].z = fmaf(a, w.z, acc[j].z);
      acc[j].w = fmaf(a, w.w, acc[j].w);
    }
  }
  #pragma unroll
  for (int j = 0; j < 4; ++j) {
    int gr = row0 + rsub + (j << 3);
    if (gr < M) {
      ushort4 bb;
      bb.x = f2bf(acc[j].x); bb.y = f2bf(acc[j].y);
      bb.z = f2bf(acc[j].z); bb.w = f2bf(acc[j].w);
      *(ushort4*)&Cb[(size_t)gr * 128 + c4] = bb;
    }
  }
}

// 4096 elems/block, 16/thread, in-place safe (each thread reads its own 16
// elements into registers before any write).
__global__ __launch_bounds__(256) void scan1_kernel(
    const int* __restrict__ in, int* __restrict__ out,
    int* __restrict__ partials, int n) {
  __shared__ int sdata[256];
  int t = threadIdx.x;
  int base = blockIdx.x * kScanElems + t * 16;
  int v[16]; int s = 0;
  #pragma unroll
  for (int j = 0; j < 16; ++j) {
    int i = base + j;
    v[j] = (i < n) ? in[i] : 0;
    s += v[j];
  }
  sdata[t] = s;
  __syncthreads();
  for (int off = 1; off < 256; off <<= 1) {
    int x = (t >= off) ? sdata[t - off] : 0;
    __syncthreads();
    sdata[t] += x;
    __syncthreads();
  }
  int run = sdata[t] - s;
  #pragma unroll
  for (int j = 0; j < 16; ++j) {
    int i = base + j;
    if (i < n) out[i] = run;
    run += v[j];
  }
  if (t == 255) partials[blockIdx.x] = sdata[255];
}

__global__ __launch_bounds__(256) void scan2_kernel(int* partials, int nb) {
  __shared__ int sdata[256];
  int t = threadIdx.x;
  sdata[t] = (t < nb) ? partials[t] : 0;
  __syncthreads();
  for (int off = 1; off < 256; off <<= 1) {
    int x = (t >= off) ? sdata[t - off] : 0;
    __syncthreads();
    sdata[t] += x;
    __syncthreads();
  }
  if (t < nb) partials[t] = (t == 0) ? 0 : sdata[t - 1];
}

__global__ __launch_bounds__(256) void scan3_kernel(
    int* __restrict__ out, const int* __restrict__ partials, int n, int total) {
  int i = blockIdx.x * 256 + threadIdx.x;
  if (i < n) out[i] += partials[i >> 12];  // kScanElems = 2^12
  if (i == 0) out[n] = total;
}

// One block per coarse bucket; gathers the bucket's 544 fragments via LDS
// binary search, stages records in LDS, fine-sorts 256 bins.
// Block-uniform fallback (no LDS recs) if the bucket exceeds kCap.
__global__ __launch_bounds__(256) void finesort_kernel(
    const int* __restrict__ G, const int* __restrict__ Loc,
    const int2* __restrict__ stag, int* __restrict__ row_ptr,
    int2* __restrict__ edges) {
  __shared__ int2 recs[kCap];     // 34.8KB
  __shared__ int off[kNBA + 1];   // fragment offsets within bucket
  __shared__ int lrow[kNBA];      // fragment local offsets in block regions
  __shared__ int fcnt[kFB];
  __shared__ int fcur[kFB];
  int t = threadIdx.x;
  int b = blockIdx.x;
  int s = G[(size_t)b * kNBA];
  // G row and Loc row are contiguous; +1 fetches next bucket's start.
  for (int k = t; k < kNBA; k += 256) {
    off[k] = G[(size_t)b * kNBA + k] - s;
    lrow[k] = Loc[(size_t)b * kNBA + k];
  }
  if (t == 0) off[kNBA] = G[(size_t)(b + 1) * kNBA] - s;  // b=kNCB-1 -> G[kGN]=kTE
  fcnt[t] = 0;
  __syncthreads();
  int cnt = off[kNBA];
  if (cnt <= kCap) {
    for (int i = t; i < cnt; i += 256) {
      int lo = 0, hi = kNBA;  // off[lo] <= i < off[hi]
      while (hi - lo > 1) {
        int mid = (lo + hi) >> 1;
        if (off[mid] <= i) lo = mid; else hi = mid;
      }
      int2 r = stag[(size_t)lo * kEPB + lrow[lo] + (i - off[lo])];
      recs[i] = r;
      atomicAdd(&fcnt[((unsigned)r.x) >> 24], 1);
    }
    __syncthreads();
    int own = fcnt[t];
    for (int o = 1; o < kFB; o <<= 1) {
      int x = (t >= o) ? fcnt[t - o] : 0;
      __syncthreads();
      fcnt[t] += x;
      __syncthreads();
    }
    int excl = fcnt[t] - own;
    int bin = (b << 8) + t;
    if (bin < kTB) row_ptr[bin] = s + excl;
    if (b == 0 && t == 0) row_ptr[kTB] = kTE;
    fcur[t] = s + excl;
    __syncthreads();
    for (int i = t; i < cnt; i += 256) {
      int2 rec = recs[i];
      unsigned f = ((unsigned)rec.x) >> 24;
      int slot = atomicAdd(&fcur[f], 1);  // LDS atomic
      edges[slot] = make_int2(rec.x & 0x00FFFFFF, rec.y);
    }
  } else {
    // fallback: gather twice (binary search twice), no LDS recs
    for (int i = t; i < cnt; i += 256) {
      int lo = 0, hi = kNBA;
      while (hi - lo > 1) {
        int mid = (lo + hi) >> 1;
        if (off[mid] <= i) lo = mid; else hi = mid;
      }
      int2 r = stag[(size_t)lo * kEPB + lrow[lo] + (i - off[lo])];
      atomicAdd(&fcnt[((unsigned)r.x) >> 24], 1);
    }
    __syncthreads();
    int own = fcnt[t];
    for (int o = 1; o < kFB; o <<= 1) {
      int x = (t >= o) ? fcnt[t - o] : 0;
      __syncthreads();
      fcnt[t] += x;
      __syncthreads();
    }
    int excl = fcnt[t] - own;
    int bin = (b << 8) + t;
    if (bin < kTB) row_ptr[bin] = s + excl;
    if (b == 0 && t == 0) row_ptr[kTB] = kTE;
    fcur[t] = s + excl;
    __syncthreads();
    for (int i = t; i < cnt; i += 256) {
      int lo = 0, hi = kNBA;
      while (hi - lo > 1) {
        int mid = (lo + hi) >> 1;
        if (off[mid] <= i) lo = mid; else hi = mid;
      }
      int2 rec = stag[(size_t)lo * kEPB + lrow[lo] + (i - off[lo])];
      unsigned f = ((unsigned)rec.x) >> 24;
      int slot = atomicAdd(&fcur[f], 1);
      edges[slot] = make_int2(rec.x & 0x00FFFFFF, rec.y);
    }
  }
}

// Fused Q/K projection: one LDS tile of A, two K-loops (Wq -> fp32, Wk -> bf16).
__global__ __launch_bounds__(256) void gemm128_qk_kernel(
    const float* __restrict__ A, const float* __restrict__ Wq,
    const float* __restrict__ Wk, float* __restrict__ Qf,
    unsigned short* __restrict__ Kb, int M) {
  __shared__ float As[64 * 132];
  int t = threadIdx.x;
  int row0 = blockIdx.x << 6;
  #pragma unroll
  for (int i = 0; i < 8; ++i) {
    int f = t + (i << 8);
    int r = f >> 5, c4 = (f & 31) << 2;
    int gr = row0 + r;
    float4 v = make_float4(0.f, 0.f, 0.f, 0.f);
    if (gr < M) v = *(const float4*)&A[(size_t)gr * 128 + c4];
    *(float4*)&As[r * 132 + c4] = v;
  }
  __syncthreads();
  int wcol = t & 31;
  int c4 = wcol << 2;
  int rsub = t >> 5;
  float4 acc[8];
  const float4* Wq4 = (const float4*)Wq;
  const float4* Wk4 = (const float4*)Wk;
  #pragma unroll
  for (int j = 0; j < 8; ++j) acc[j] = make_float4(0.f, 0.f, 0.f, 0.f);
  #pragma unroll 4
  for (int k = 0; k < 128; ++k) {
    float4 w = Wq4[k * 32 + wcol];
    #pragma unroll
    for (int j = 0; j < 8; ++j) {
      float a = As[(rsub + (j << 3)) * 132 + k];
      acc[j].x = fmaf(a, w.x, acc[j].x);
      acc[j].y = fmaf(a, w.y, acc[j].y);
      acc[j].z = fmaf(a, w.z, acc[j].z);
      acc[j].w = fmaf(a, w.w, acc[j].w);
    }
  }
  #pragma unroll
  for (int j = 0; j < 8; ++j) {
    int gr = row0 + rsub + (j << 3);
    if (gr < M) *(float4*)&Qf[(size_t)gr * 128 + c4] = acc[j];
  }
  #pragma unroll
  for (int j = 0; j < 8; ++j) acc[j] = make_float4(0.f, 0.f, 0.f, 0.f);
  #pragma unroll 4
  for (int k = 0; k < 128; ++k) {
    float4 w = Wk4[k * 32 + wcol];
    #pragma unroll
    for (int j = 0; j < 8; ++j) {
      float a = As[(rsub + (j << 3)) * 132 + k];
      acc[j].x = fmaf(a, w.x, acc[j].x);
      acc[j].y = fmaf(a, w.y, acc[j].y);
      acc[j].z = fmaf(a, w.z, acc[j].z);
      acc[j].w = fmaf(a, w.w, acc[j].w);
    }
  }
  #pragma unroll
  for (int j = 0; j < 8; ++j) {
    int gr = row0 + rsub + (j << 3);
    if (gr < M) {
      ushort4 b;
      b.x = f2bf(acc[j].x); b.y = f2bf(acc[j].y);
      b.z = f2bf(acc[j].z); b.w = f2bf(acc[j].w);
      *(ushort4*)&Kb[(size_t)gr * 128 + c4] = b;
    }
  }
}

// Fused double-unpool + gc2 projection:
//   crf_row[r] = H2[assign1[assign0[r]]] + H1[assign0[r]] + Gcn[r]
//   crf_h[r]   = crf_row (output), Cb[r] = bf16(crf_row @ W2)
__global__ __launch_bounds__(256) void unpool_gemm40_kernel(
    const float* __restrict__ H2, const float* __restrict__ H1,
    const float* __restrict__ Gcn, const int* __restrict__ assign0,
    const int* __restrict__ assign1, const float* __restrict__ W,
    float* __restrict__ crf_out, unsigned short* __restrict__ Cb, int M) {
  __shared__ float Ws[128 * 40];
  __shared__ float As[64 * 132];
  __shared__ int ia0[64], ia1[64];
  int t = threadIdx.x;
  int row0 = blockIdx.x << 6;
  #pragma unroll
  for (int i = 0; i < 5; ++i)
    ((float4*)Ws)[t + i * 256] = ((const float4*)W)[t + i * 256];
  if (t < 64) {
    int gr = row0 + t;
    int a0 = (gr < M) ? assign0[gr] : 0;
    ia0[t] = a0;
    ia1[t] = assign1[a0];
  }
  __syncthreads();
  #pragma unroll
  for (int i = 0; i < 8; ++i) {
    int f = t + (i << 8);
    int r = f >> 5, c4 = (f & 31) << 2;
    int gr = row0 + r;
    float4 v = make_float4(0.f, 0.f, 0.f, 0.f);
    if (gr < M) {
      float4 v2 = *(const float4*)&H2[(size_t)ia1[r] * 128 + c4];
      float4 v1 = *(const float4*)&H1[(size_t)ia0[r] * 128 + c4];
      float4 vg = *(const float4*)&Gcn[(size_t)gr * 128 + c4];
      v = make_float4(v2.x + v1.x + vg.x, v2.y + v1.y + vg.y,
                      v2.z + v1.z + vg.z, v2.w + v1.w + vg.w);
      *(float4*)&crf_out[(size_t)gr * 128 + c4] = v;
    }
    *(float4*)&As[r * 132 + c4] = v;
  }
  __syncthreads();
  int r = t >> 2;
  int cg = (t & 3) * 10;
  float acc[10];
  #pragma unroll
  for (int j = 0; j < 10; ++j) acc[j] = 0.f;
  for (int k = 0; k < 128; ++k) {
    float a = As[r * 132 + k];
    #pragma unroll
    for (int j = 0; j < 10; ++j) acc[j] = fmaf(a, Ws[k * 40 + cg + j], acc[j]);
  }
  int gr = row0 + r;
  if (gr < M) {
    #pragma unroll
    for (int j = 0; j < 10; ++j) Cb[(size_t)gr * 40 + cg + j] = f2bf(acc[j]);
  }
}

// ---------------------------------------------------------------------------
// Pull-SpMM over CSR: one wave per dst row, 128 cols (2/lane), 4-way MLP.
// ---------------------------------------------------------------------------
template <bool BF16>
__global__ __launch_bounds__(256) void spmm128_kernel(
    const int* __restrict__ row_ptr, const int2* __restrict__ edges,
    const void* __restrict__ Xv, float* __restrict__ Y,
    const float* __restrict__ bias, int nrows, int do_relu) {
  int wid = (blockIdx.x * 256 + threadIdx.x) >> 6;
  int lane = threadIdx.x & 63;
  if (wid >= nrows) return;
  int start = row_ptr[wid], end = row_ptr[wid + 1];
  const unsigned short* Xb = (const unsigned short*)Xv;
  const float* Xf = (const float*)Xv;
  float2 accA = make_float2(0.f, 0.f), accB = make_float2(0.f, 0.f);
  for (int base = start; base < end; base += 64) {
    int cnt = end - base; if (cnt > 64) cnt = 64;
    int2 e_l = make_int2(0, 0);
    if (lane < cnt) e_l = edges[base + lane];
    int j = 0;
    for (; j + 4 <= cnt; j += 4) {
      int s0 = __shfl(e_l.x, j + 0), s1 = __shfl(e_l.x, j + 1);
      int s2 = __shfl(e_l.x, j + 2), s3 = __shfl(e_l.x, j + 3);
      float v0 = __int_as_float(__shfl(e_l.y, j + 0));
      float v1 = __int_as_float(__shfl(e_l.y, j + 1));
      float v2 = __int_as_float(__shfl(e_l.y, j + 2));
      float v3 = __int_as_float(__shfl(e_l.y, j + 3));
      if (BF16) {
        unsigned int u0 = *(const unsigned int*)(Xb + (size_t)s0 * 128 + lane * 2);
        unsigned int u1 = *(const unsigned int*)(Xb + (size_t)s1 * 128 + lane * 2);
        unsigned int u2 = *(const unsigned int*)(Xb + (size_t)s2 * 128 + lane * 2);
        unsigned int u3 = *(const unsigned int*)(Xb + (size_t)s3 * 128 + lane * 2);
        accA.x = fmaf(v0, bf_lo(u0), accA.x); accA.y = fmaf(v0, bf_hi(u0), accA.y);
        accB.x = fmaf(v1, bf_lo(u1), accB.x); accB.y = fmaf(v1, bf_hi(u1), accB.y);
        accA.x = fmaf(v2, bf_lo(u2), accA.x); accA.y = fmaf(v2, bf_hi(u2), accA.y);
        accB.x = fmaf(v3, bf_lo(u3), accB.x); accB.y = fmaf(v3, bf_hi(u3), accB.y);
      } else {
        float2 x0 = *(const float2*)(Xf + (size_t)s0 * 128 + lane * 2);
        float2 x1 = *(const float2*)(Xf + (size_t)s1 * 128 + lane * 2);
        float2 x2 = *(const float2*)(Xf + (size_t)s2 * 128 + lane * 2);
        float2 x3 = *(const float2*)(Xf + (size_t)s3 * 128 + lane * 2);
        accA.x = fmaf(v0, x0.x, accA.x); accA.y = fmaf(v0, x0.y, accA.y);
        accB.x = fmaf(v1, x1.x, accB.x); accB.y = fmaf(v1, x1.y, accB.y);
        accA.x = fmaf(v2, x2.x, accA.x); accA.y = fmaf(v2, x2.y, accA.y);
        accB.x = fmaf(v3, x3.x, accB.x); accB.y = fmaf(v3, x3.y, accB.y);
      }
    }
    for (; j < cnt; ++j) {
      int src = __shfl(e_l.x, j);
      float val = __int_as_float(__shfl(e_l.y, j));
      if (BF16) {
        unsigned int u = *(const unsigned int*)(Xb + (size_t)src * 128 + lane * 2);
        accA.x = fmaf(val, bf_lo(u), accA.x);
        accA.y = fmaf(val, bf_hi(u), accA.y);
      } else {
        float2 xv = *(const float2*)(Xf + (size_t)src * 128 + lane * 2);
        accA.x = fmaf(val, xv.x, accA.x);
        accA.y = fmaf(val, xv.y, accA.y);
      }
    }
  }
  float2 acc = make_float2(accA.x + accB.x, accA.y + accB.y);
  if (bias) { acc.x += bias[lane * 2]; acc.y += bias[lane * 2 + 1]; }
  if (do_relu) { acc.x = fmaxf(acc.x, 0.f); acc.y = fmaxf(acc.y, 0.f); }
  *(float2*)&Y[(size_t)wid * 128 + lane * 2] = acc;
}

// Pool (T-graph pull sum) fused with nwgt-embedding add, 4-way MLP.
__global__ __launch_bounds__(256) void pool_emb_kernel(
    const int* __restrict__ row_ptr, const int2* __restrict__ edges,
    const float* __restrict__ X, const int* __restrict__ nwgt,
    const float* __restrict__ emb, float* __restrict__ Hpool,
    float* __restrict__ H0, unsigned short* __restrict__ H0b, int nrows) {
  int wid = (blockIdx.x * 256 + threadIdx.x) >> 6;
  int lane = threadIdx.x & 63;
  if (wid >= nrows) return;
  int start = row_ptr[wid], end = row_ptr[wid + 1];
  float2 accA = make_float2(0.f, 0.f), accB = make_float2(0.f, 0.f);
  for (int base = start; base < end; base += 64) {
    int cnt = end - base; if (cnt > 64) cnt = 64;
    int s_l = 0;
    if (lane < cnt) s_l = edges[base + lane].x;
    int j = 0;
    for (; j + 4 <= cnt; j += 4) {
      int s0 = __shfl(s_l, j + 0), s1 = __shfl(s_l, j + 1);
      int s2 = __shfl(s_l, j + 2), s3 = __shfl(s_l, j + 3);
      float2 x0 = *(const float2*)&X[(size_t)s0 * 128 + lane * 2];
      float2 x1 = *(const float2*)&X[(size_t)s1 * 128 + lane * 2];
      float2 x2 = *(const float2*)&X[(size_t)s2 * 128 + lane * 2];
      float2 x3 = *(const float2*)&X[(size_t)s3 * 128 + lane * 2];
      accA.x += x0.x + x2.x; accA.y += x0.y + x2.y;
      accB.x += x1.x + x3.x; accB.y += x1.y + x3.y;
    }
    for (; j < cnt; ++j) {
      int src = __shfl(s_l, j);
      float2 xv = *(const float2*)&X[(size_t)src * 128 + lane * 2];
      accA.x += xv.x; accA.y += xv.y;
    }
  }
  float2 acc = make_float2(accA.x + accB.x, accA.y + accB.y);
  *(float2*)&Hpool[(size_t)wid * 128 + lane * 2] = acc;
  float2 ev = *(const float2*)&emb[(size_t)nwgt[wid] * 128 + lane * 2];
  float2 h0 = make_float2(acc.x + ev.x, acc.y + ev.y);
  *(float2*)&H0[(size_t)wid * 128 + lane * 2] = h0;
  unsigned int packed = ((unsigned int)f2bf(h0.x)) | (((unsigned int)f2bf(h0.y)) << 16);
  *(unsigned int*)(H0b + (size_t)wid * 128 + lane * 2) = packed;
}

__global__ __launch_bounds__(256) void spmm40_kernel(
    const int* __restrict__ row_ptr, const int2* __restrict__ edges,
    const unsigned short* __restrict__ Xb, float* __restrict__ Y,
    const float* __restrict__ bias, int nrows) {
  int wid = (blockIdx.x * 256 + threadIdx.x) >> 6;
  int lane = threadIdx.x & 63;
  if (wid >= nrows) return;
  int start = row_ptr[wid], end = row_ptr[wid + 1];
  float accA = 0.f, accB = 0.f;
  for (int base = start; base < end; base += 64) {
    int cnt = end - base; if (cnt > 64) cnt = 64;
    int2 e_l = make_int2(0, 0);
    if (lane < cnt) e_l = edges[base + lane];
    int j = 0;
    for (; j + 4 <= cnt; j += 4) {
      int s0 = __shfl(e_l.x, j + 0), s1 = __shfl(e_l.x, j + 1);
      int s2 = __shfl(e_l.x, j + 2), s3 = __shfl(e_l.x, j + 3);
      float v0 = __int_as_float(__shfl(e_l.y, j + 0));
      float v1 = __int_as_float(__shfl(e_l.y, j + 1));
      float v2 = __int_as_float(__shfl(e_l.y, j + 2));
      float v3 = __int_as_float(__shfl(e_l.y, j + 3));
      if (lane < 40) {
        unsigned short u0 = Xb[(size_t)s0 * 40 + lane];
        unsigned short u1 = Xb[(size_t)s1 * 40 + lane];
        unsigned short u2 = Xb[(size_t)s2 * 40 + lane];
        unsigned short u3 = Xb[(size_t)s3 * 40 + lane];
        accA = fmaf(v0, __uint_as_float(((unsigned int)u0) << 16), accA);
        accB = fmaf(v1, __uint_as_float(((unsigned int)u1) << 16), accB);
        accA = fmaf(v2, __uint_as_float(((unsigned int)u2) << 16), accA);
        accB = fmaf(v3, __uint_as_float(((unsigned int)u3) << 16), accB);
      }
    }
    for (; j < cnt; ++j) {
      int src = __shfl(e_l.x, j);
      float val = __int_as_float(__shfl(e_l.y, j));
      if (lane < 40) {
        unsigned short u = Xb[(size_t)src * 40 + lane];
        accA = fmaf(val, __uint_as_float(((unsigned int)u) << 16), accA);
      }
    }
  }
  if (lane < 40) Y[(size_t)wid * 40 + lane] = accA + accB + bias[lane];
}

// ---------------------------------------------------------------------------
// Fused CRF row kernel, 4 edges per step: batched k/h0 gathers (8 loads in
// flight), 4 interleaved butterfly dot-reductions, one online-softmax update.
// ---------------------------------------------------------------------------
__global__ __launch_bounds__(256) void crf_fused_kernel(
    const int* __restrict__ row_ptr, const int2* __restrict__ edges,
    const float* __restrict__ Q, const unsigned short* __restrict__ Kb,
    const float* __restrict__ H0, const unsigned short* __restrict__ H0b,
    float* __restrict__ Y, const float* __restrict__ alpha_p,
    const float* __restrict__ beta_p, int nrows) {
  int wid = (blockIdx.x * 256 + threadIdx.x) >> 6;
  int lane = threadIdx.x & 63;
  if (wid >= nrows) return;
  int start = row_ptr[wid], end = row_ptr[wid + 1];
  float2 qv = *(const float2*)&Q[(size_t)wid * 128 + lane * 2];
  const float kScale = 0.08838834764831845f;  // 1/sqrt(128)
  float m = -3.4e38f, z = 0.f;
  float2 msg = make_float2(0.f, 0.f);
  for (int base = start; base < end; base += 64) {
    int cnt = end - base; if (cnt > 64) cnt = 64;
    int s_l = 0;
    if (lane < cnt) s_l = edges[base + lane].x;
    int j = 0;
    for (; j + 4 <= cnt; j += 4) {
      int s0 = __shfl(s_l, j + 0), s1 = __shfl(s_l, j + 1);
      int s2 = __shfl(s_l, j + 2), s3 = __shfl(s_l, j + 3);
      unsigned int k0 = *(const unsigned int*)(Kb + (size_t)s0 * 128 + lane * 2);
      unsigned int k1 = *(const unsigned int*)(Kb + (size_t)s1 * 128 + lane * 2);
      unsigned int k2 = *(const unsigned int*)(Kb + (size_t)s2 * 128 + lane * 2);
      unsigned int k3 = *(const unsigned int*)(Kb + (size_t)s3 * 128 + lane * 2);
      unsigned int h0 = *(const unsigned int*)(H0b + (size_t)s0 * 128 + lane * 2);
      unsigned int h1 = *(const unsigned int*)(H0b + (size_t)s1 * 128 + lane * 2);
      unsigned int h2 = *(const unsigned int*)(H0b + (size_t)s2 * 128 + lane * 2);
      unsigned int h3 = *(const unsigned int*)(H0b + (size_t)s3 * 128 + lane * 2);
      float p0 = qv.x * bf_lo(k0) + qv.y * bf_hi(k0);
      float p1 = qv.x * bf_lo(k1) + qv.y * bf_hi(k1);
      float p2 = qv.x * bf_lo(k2) + qv.y * bf_hi(k2);
      float p3 = qv.x * bf_lo(k3) + qv.y * bf_hi(k3);
      #pragma unroll
      for (int d = 32; d >= 1; d >>= 1) {
        p0 += __shfl_xor(p0, d);
        p1 += __shfl_xor(p1, d);
        p2 += __shfl_xor(p2, d);
        p3 += __shfl_xor(p3, d);
      }
      p0 *= kScale; p1 *= kScale; p2 *= kScale; p3 *= kScale;
      float pm = fmaxf(fmaxf(p0, p1), fmaxf(p2, p3));
      float mn = fmaxf(m, pm);
      float corr = __expf(m - mn);
      float w0 = __expf(p0 - mn), w1 = __expf(p1 - mn);
      float w2 = __expf(p2 - mn), w3 = __expf(p3 - mn);
      z = z * corr + (w0 + w1) + (w2 + w3);
      msg.x = msg.x * corr + w0 * bf_lo(h0) + w1 * bf_lo(h1)
                           + w2 * bf_lo(h2) + w3 * bf_lo(h3);
      msg.y = msg.y * corr + w0 * bf_hi(h0) + w1 * bf_hi(h1)
                           + w2 * bf_hi(h2) + w3 * bf_hi(h3);
      m = mn;
    }
    for (; j < cnt; ++j) {
      int src = __shfl(s_l, j);
      unsigned int ku = *(const unsigned int*)(Kb + (size_t)src * 128 + lane * 2);
      unsigned int hu = *(const unsigned int*)(H0b + (size_t)src * 128 + lane * 2);
      float p = qv.x * bf_lo(ku) + qv.y * bf_hi(ku);
      #pragma unroll
      for (int d = 32; d >= 1; d >>= 1) p += __shfl_xor(p, d);
      p *= kScale;
      float mn = fmaxf(m, p);
      float corr = __expf(m - mn);
      float w = __expf(p - mn);
      z = z * corr + w;
      msg.x = msg.x * corr + w * bf_lo(hu);
      msg.y = msg.y * corr + w * bf_hi(hu);
      m = mn;
    }
  }
  float alpha = *alpha_p, beta = *beta_p;
  float inv = 1.0f / (z + 1e-16f);
  float2 h0i = *(const float2*)&H0[(size_t)wid * 128 + lane * 2];
  float sc = 1.0f / (alpha + beta);
  float2 o;
  o.x = (alpha * h0i.x + beta * (msg.x * inv)) * sc;
  o.y = (alpha * h0i.y + beta * (msg.y * inv)) * sc;
  *(float2*)&Y[(size_t)wid * 128 + lane * 2] = o;
}

}  // namespace

// ---------------------------------------------------------------------------
extern "C" void kernel_launch(void* const* d_in, const int* in_sizes, int n_in,
                              void* d_out, int out_size, void* d_ws, size_t ws_size,
                              hipStream_t stream) {
  const float* x       = (const float*)d_in[0];
  const int*   A0_idx  = (const int*)d_in[1];
  const float* A0_val  = (const float*)d_in[2];
  const int*   A1_idx  = (const int*)d_in[3];
  const int*   A2_idx  = (const int*)d_in[5];
  const int*   assign0 = (const int*)d_in[7];
  const int*   assign1 = (const int*)d_in[8];
  const int*   nwgt1   = (const int*)d_in[9];
  const int*   nwgt2   = (const int*)d_in[10];
  const float* gc1_W   = (const float*)d_in[11];
  const float* gc1_b   = (const float*)d_in[12];
  const float* gc2_W   = (const float*)d_in[13];
  const float* gc2_b   = (const float*)d_in[14];
  const float* c1_Wq   = (const float*)d_in[15];
  const float* c1_Wk   = (const float*)d_in[16];
  const float* c1_emb  = (const float*)d_in[17];
  const float* c1_al   = (const float*)d_in[18];
  const float* c1_be   = (const float*)d_in[19];
  const float* c2_Wq   = (const float*)d_in[20];
  const float* c2_Wk   = (const float*)d_in[21];
  const float* c2_emb  = (const float*)d_in[22];
  const float* c2_al   = (const float*)d_in[23];
  const float* c2_be   = (const float*)d_in[24];

  float* out_g = (float*)d_out;                      // [N0, 40]
  float* gcn_h = out_g + (size_t)kN0 * 40;           // [N0, 128]
  float* crf_h = gcn_h + (size_t)kN0 * 128;          // [N0, 128]

  // ---- workspace carving ----
  char* ws = (char*)d_ws;
  size_t off = 0;
  auto carve = [&](size_t bytes) -> void* {
    void* p = ws + off;
    off += (bytes + 511) & ~(size_t)511;
    return p;
  };
  int*   G        = (int*)carve((size_t)(kGN + 1) * 4);    // 1.38 MB bucket matrix
  int*   Loc      = (int*)carve((size_t)kGN * 4);          // 1.38 MB local offsets
  int*   row_ptr  = (int*)carve((size_t)(kTB + 1) * 4);
  int*   partials = (int*)carve(1024);
  int2*  edges    = (int2*)carve((size_t)kTE * 8);         // 17.8 MB
  float* h1_crf   = (float*)carve((size_t)kN1 * 128 * 4);  // 12.8 MB, long-lived
  char*  arena    = (char*)carve(51200000 + 4096);         // reused overlays
  // Overlays (byte offsets; lifetimes vs launch order):
  unsigned short* xWb   = (unsigned short*)(arena);              // [sortblk-gemm .. gc1 spmm]
  int2* stag_rec = (int2*)(arena + 25600000);                    // [sortblk .. finesort], 544*4096*8=17.8MB
  float* h1_pool = (float*)(arena);                              // [pool1 .. qk1]
  float* h0_1    = (float*)(arena + 12800000);                   // [pool1 .. crf1]
  unsigned short* h0_1b = (unsigned short*)(arena + 25600000);   // [pool1 .. crf1]
  float* q1      = (float*)(arena + 32000000);                   // [qk1 .. crf1]
  unsigned short* k1b   = (unsigned short*)(arena + 44800000);   // [qk1 .. crf1]
  float* h2_pool = (float*)(arena);                              // [pool2 .. qk2]
  float* h0_2    = (float*)(arena + 3200000);                    // [pool2 .. crf2]
  unsigned short* h0_2b = (unsigned short*)(arena + 6400000);    // [pool2 .. crf2]
  float* q2      = (float*)(arena + 8000000);                    // [qk2 .. crf2]
  unsigned short* k2b   = (unsigned short*)(arena + 11200000);   // [qk2 .. crf2]
  float* h2_crf  = (float*)(arena + 12800000);                   // [crf2 .. unpool]
  unsigned short* hW2b  = (unsigned short*)(arena);              // [unpool_gemm40 .. spmm40]
  // stag_rec [25.6M,43.45M) is disjoint from xWb [0,25.6M) during the
  // sortblk+gemm / finesort dispatches and dead before pool1 writes h0_1b.

  // ---- 1. CSR build: sortblk(+gc1 gemm) -> scan(G) -> finesort ----
  sortblk_gemm_kernel<<<kNBA + kGemmBlocks, 256, 0, stream>>>(
      A0_idx, A0_val, A1_idx, A2_idx, assign0, assign1, G, Loc, stag_rec,
      x, gc1_W, xWb, kN0);
  scan1_kernel<<<kNBLK_G, 256, 0, stream>>>(G, G, partials, kGN);
  scan2_kernel<<<1, 256, 0, stream>>>(partials, kNBLK_G);
  scan3_kernel<<<(kGN + 255) / 256, 256, 0, stream>>>(G, partials, kGN, kTE);
  finesort_kernel<<<kNCB, 256, 0, stream>>>(G, Loc, stag_rec, row_ptr, edges);

  // ---- 2. gc1 aggregation: h = relu(A0 @ (x W1) + b1) -> gcn_hidden ----
  spmm128_kernel<true><<<(kN0 + 3) / 4, 256, 0, stream>>>(row_ptr, edges, xWb,
                                                          gcn_h, gc1_b, kN0, 1);
  // ---- 3. level-1 pool(+emb) + QK + CRF ----
  pool_emb_kernel<<<(kN1 + 3) / 4, 256, 0, stream>>>(row_ptr + kBO3, edges, gcn_h,
                                                     nwgt1, c1_emb, h1_pool, h0_1,
                                                     h0_1b, kN1);
  gemm128_qk_kernel<<<(kN1 + 63) / 64, 256, 0, stream>>>(h1_pool, c1_Wq, c1_Wk,
                                                         q1, k1b, kN1);
  crf_fused_kernel<<<(kN1 + 3) / 4, 256, 0, stream>>>(row_ptr + kBO1, edges, q1, k1b,
                                                      h0_1, h0_1b, h1_crf, c1_al,
                                                      c1_be, kN1);
  // ---- 4. level-2 pool(+emb) + QK + CRF ----
  pool_emb_kernel<<<(kN2 + 3) / 4, 256, 0, stream>>>(row_ptr + kBO4, edges, h1_crf,
                                                     nwgt2, c2_emb, h2_pool, h0_2,
                                                     h0_2b, kN2);
  gemm128_qk_kernel<<<(kN2 + 63) / 64, 256, 0, stream>>>(h2_pool, c2_Wq, c2_Wk,
                                                         q2, k2b, kN2);
  crf_fused_kernel<<<(kN2 + 3) / 4, 256, 0, stream>>>(row_ptr + kBO2, edges, q2, k2b,
                                                      h0_2, h0_2b, h2_crf, c2_al,
                                                      c2_be, kN2);
  // ---- 5+6. fused double unpool -> crf_hidden, + gc2 projection (bf16) ----
  unpool_gemm40_kernel<<<(kN0 + 63) / 64, 256, 0, stream>>>(
      h2_crf, h1_crf, gcn_h, assign0, assign1, gc2_W, crf_h, hW2b, kN0);
  spmm40_kernel<<<(kN0 + 3) / 4, 256, 0, stream>>>(row_ptr, edges, hW2b,
                                                   out_g, gc2_b, kN0);
}